// Round 6
// baseline (143.409 us; speedup 1.0000x reference)
//
#include <hip/hip_runtime.h>

// PointPillarScatter: KITTI grid 432x496, 64 channels, B derived from out_size
#define PNX 432
#define PNY 496
#define PC  64

typedef float f32x4 __attribute__((ext_vector_type(4)));
typedef int   i32x4 __attribute__((ext_vector_type(4)));

// One thread per pillar: map[b*NY*NX + z + y*NX + x] = p (cells unique).
// Block 0 also zeroes the 64-float zero-row used by the gather's row fallback.
__global__ __launch_bounds__(256) void pps_scatter_idx(const int* __restrict__ coords,
                                                       int* __restrict__ map,
                                                       float* __restrict__ zrow, int P) {
    int p = blockIdx.x * blockDim.x + threadIdx.x;
    if (blockIdx.x == 0 && threadIdx.x < PC) zrow[threadIdx.x] = 0.f;
    if (p >= P) return;
    int b = coords[p * 4 + 0];
    int z = coords[p * 4 + 1];
    int y = coords[p * 4 + 2];
    int x = coords[p * 4 + 3];
    map[(size_t)b * (PNY * PNX) + z + y * PNX + x] = p;
}

// R2 winner structure (best of R2-R5 sweep): one thread per 4 consecutive
// cells; empty cells read the L1-hot zero-row so every load is unconditional;
// 16 loads batched in flight before 16 transposed nontemporal stores. Every
// nt store instruction is a fully dense 1KB wave-level burst (R3 lesson:
// nt + partial density = 2x DRAM write cost; R5 lesson: plain stores = +15%).
// This round's single variable: nontemporal LOADS on map/feat (read-once data,
// skip L2 allocate).
__global__ __launch_bounds__(256) void pps_gather(const float* __restrict__ feat,
                                                  const int* __restrict__ map,
                                                  const float* __restrict__ zrow,
                                                  float* __restrict__ out, int ncell4) {
    int t = blockIdx.x * blockDim.x + threadIdx.x;
    if (t >= ncell4) return;
    int cell0 = t << 2;
    int b   = cell0 / (PNY * PNX);       // 4-cell groups never cross a batch (NY*NX % 4 == 0)
    int loc = cell0 - b * (PNY * PNX);
    i32x4 pp = __builtin_nontemporal_load(reinterpret_cast<const i32x4*>(map + cell0));
    const float* r0 = (pp.x >= 0) ? feat + (size_t)pp.x * PC : zrow;
    const float* r1 = (pp.y >= 0) ? feat + (size_t)pp.y * PC : zrow;
    const float* r2 = (pp.z >= 0) ? feat + (size_t)pp.z * PC : zrow;
    const float* r3 = (pp.w >= 0) ? feat + (size_t)pp.w * PC : zrow;
    const size_t plane = (size_t)PNY * PNX;
    float* obase = out + (size_t)b * PC * plane + loc;
#pragma unroll
    for (int cc = 0; cc < PC; cc += 16) {
        f32x4 f0[4], f1[4], f2[4], f3[4];
#pragma unroll
        for (int j = 0; j < 4; ++j) {
            f0[j] = __builtin_nontemporal_load(reinterpret_cast<const f32x4*>(r0 + cc + j * 4));
            f1[j] = __builtin_nontemporal_load(reinterpret_cast<const f32x4*>(r1 + cc + j * 4));
            f2[j] = __builtin_nontemporal_load(reinterpret_cast<const f32x4*>(r2 + cc + j * 4));
            f3[j] = __builtin_nontemporal_load(reinterpret_cast<const f32x4*>(r3 + cc + j * 4));
        }
#pragma unroll
        for (int j = 0; j < 4; ++j) {
#pragma unroll
            for (int k = 0; k < 4; ++k) {
                f32x4 v = { f0[j][k], f1[j][k], f2[j][k], f3[j][k] };
                __builtin_nontemporal_store(
                    v, reinterpret_cast<f32x4*>(obase + (size_t)(cc + j * 4 + k) * plane));
            }
        }
    }
}

// ---------- fallback path (ws too small): zero + direct scatter ----------

__global__ __launch_bounds__(256) void pps_zero(float4* __restrict__ out4, int n4) {
    int i = blockIdx.x * blockDim.x + threadIdx.x;
    if (i < n4) out4[i] = make_float4(0.f, 0.f, 0.f, 0.f);
}

__global__ __launch_bounds__(256) void pps_scatter_feat(const float* __restrict__ feat,
                                                        const int* __restrict__ coords,
                                                        float* __restrict__ out, int total) {
    int g = blockIdx.x * blockDim.x + threadIdx.x;
    if (g >= total) return;
    int p = g >> 6;      // pillar
    int c = g & 63;      // channel
    int b = coords[p * 4 + 0];
    int z = coords[p * 4 + 1];
    int y = coords[p * 4 + 2];
    int x = coords[p * 4 + 3];
    const size_t plane = (size_t)PNY * PNX;
    out[((size_t)b * PC + c) * plane + z + y * PNX + x] = feat[g];
}

extern "C" void kernel_launch(void* const* d_in, const int* in_sizes, int n_in,
                              void* d_out, int out_size, void* d_ws, size_t ws_size,
                              hipStream_t stream) {
    const float* feat   = (const float*)d_in[0];
    const int*   coords = (const int*)d_in[1];
    float* out = (float*)d_out;

    const int P = in_sizes[1] / 4;                   // coords is [P,4]
    const int B = out_size / (PC * PNY * PNX);       // derive batch from out_size
    const size_t ncell = (size_t)B * PNY * PNX;      // divisible by 4
    const size_t mapbytes = ncell * sizeof(int);
    const size_t zoff = (mapbytes + 255) & ~(size_t)255;
    const size_t need = zoff + PC * sizeof(float);

    if (ws_size >= need) {
        int*   map  = (int*)d_ws;
        float* zrow = (float*)((char*)d_ws + zoff);
        // 0xFF bytes == int32 -1 : empty-cell marker
        hipMemsetAsync(map, 0xFF, mapbytes, stream);
        pps_scatter_idx<<<(P + 255) / 256, 256, 0, stream>>>(coords, map, zrow, P);
        int n4 = (int)(ncell / 4);
        pps_gather<<<(n4 + 255) / 256, 256, 0, stream>>>(feat, map, zrow, out, n4);
    } else {
        int n4 = out_size / 4;
        pps_zero<<<(n4 + 255) / 256, 256, 0, stream>>>((float4*)out, n4);
        int total = P * PC;
        pps_scatter_feat<<<(total + 255) / 256, 256, 0, stream>>>(feat, coords, out, total);
    }
}

// Round 7
// 94.583 us; speedup vs baseline: 1.5162x; 1.5162x over previous
//
#include <hip/hip_runtime.h>

// PointPillarScatter: KITTI grid 432x496, 64 channels, B derived from out_size
// FINAL (R2 structure — best of R2-R6 single-variable sweep):
//   R2 dense-nt-store gather: 94.6 us
//   R3 8-cell/half-dense-nt: 194.9 | R4 x2-coarsen: 102.0
//   R5 plain stores: 109.0    | R6 nt loads (kills L1-hot zrow): 143.4
#define PNX 432
#define PNY 496
#define PC  64

typedef float f32x4 __attribute__((ext_vector_type(4)));

// One thread per pillar: map[b*NY*NX + z + y*NX + x] = p (cells unique).
// Block 0 also zeroes the 64-float zero-row used by the gather's row fallback.
__global__ __launch_bounds__(256) void pps_scatter_idx(const int* __restrict__ coords,
                                                       int* __restrict__ map,
                                                       float* __restrict__ zrow, int P) {
    int p = blockIdx.x * blockDim.x + threadIdx.x;
    if (blockIdx.x == 0 && threadIdx.x < PC) zrow[threadIdx.x] = 0.f;
    if (p >= P) return;
    int b = coords[p * 4 + 0];
    int z = coords[p * 4 + 1];
    int y = coords[p * 4 + 2];
    int x = coords[p * 4 + 3];
    map[(size_t)b * (PNY * PNX) + z + y * PNX + x] = p;
}

// One thread per 4 consecutive cells. Empty cells read the L1-hot zero-row so
// every load is unconditional (PLAIN loads — zrow reuse must stay cached).
// 16 loads batched in flight before 16 transposed nontemporal stores; every
// nt store instruction is a fully dense 1KB wave-level burst.
__global__ __launch_bounds__(256) void pps_gather(const float* __restrict__ feat,
                                                  const int* __restrict__ map,
                                                  const float* __restrict__ zrow,
                                                  float* __restrict__ out, int ncell4) {
    int t = blockIdx.x * blockDim.x + threadIdx.x;
    if (t >= ncell4) return;
    int cell0 = t << 2;
    int b   = cell0 / (PNY * PNX);       // 4-cell groups never cross a batch (NY*NX % 4 == 0)
    int loc = cell0 - b * (PNY * PNX);
    int4 pp = *reinterpret_cast<const int4*>(map + cell0);
    const float* r0 = (pp.x >= 0) ? feat + (size_t)pp.x * PC : zrow;
    const float* r1 = (pp.y >= 0) ? feat + (size_t)pp.y * PC : zrow;
    const float* r2 = (pp.z >= 0) ? feat + (size_t)pp.z * PC : zrow;
    const float* r3 = (pp.w >= 0) ? feat + (size_t)pp.w * PC : zrow;
    const size_t plane = (size_t)PNY * PNX;
    float* obase = out + (size_t)b * PC * plane + loc;
#pragma unroll
    for (int cc = 0; cc < PC; cc += 16) {
        f32x4 f0[4], f1[4], f2[4], f3[4];
#pragma unroll
        for (int j = 0; j < 4; ++j) {
            f0[j] = *reinterpret_cast<const f32x4*>(r0 + cc + j * 4);
            f1[j] = *reinterpret_cast<const f32x4*>(r1 + cc + j * 4);
            f2[j] = *reinterpret_cast<const f32x4*>(r2 + cc + j * 4);
            f3[j] = *reinterpret_cast<const f32x4*>(r3 + cc + j * 4);
        }
#pragma unroll
        for (int j = 0; j < 4; ++j) {
#pragma unroll
            for (int k = 0; k < 4; ++k) {
                f32x4 v = { f0[j][k], f1[j][k], f2[j][k], f3[j][k] };
                __builtin_nontemporal_store(
                    v, reinterpret_cast<f32x4*>(obase + (size_t)(cc + j * 4 + k) * plane));
            }
        }
    }
}

// ---------- fallback path (ws too small): zero + direct scatter ----------

__global__ __launch_bounds__(256) void pps_zero(float4* __restrict__ out4, int n4) {
    int i = blockIdx.x * blockDim.x + threadIdx.x;
    if (i < n4) out4[i] = make_float4(0.f, 0.f, 0.f, 0.f);
}

__global__ __launch_bounds__(256) void pps_scatter_feat(const float* __restrict__ feat,
                                                        const int* __restrict__ coords,
                                                        float* __restrict__ out, int total) {
    int g = blockIdx.x * blockDim.x + threadIdx.x;
    if (g >= total) return;
    int p = g >> 6;      // pillar
    int c = g & 63;      // channel
    int b = coords[p * 4 + 0];
    int z = coords[p * 4 + 1];
    int y = coords[p * 4 + 2];
    int x = coords[p * 4 + 3];
    const size_t plane = (size_t)PNY * PNX;
    out[((size_t)b * PC + c) * plane + z + y * PNX + x] = feat[g];
}

extern "C" void kernel_launch(void* const* d_in, const int* in_sizes, int n_in,
                              void* d_out, int out_size, void* d_ws, size_t ws_size,
                              hipStream_t stream) {
    const float* feat   = (const float*)d_in[0];
    const int*   coords = (const int*)d_in[1];
    float* out = (float*)d_out;

    const int P = in_sizes[1] / 4;                   // coords is [P,4]
    const int B = out_size / (PC * PNY * PNX);       // derive batch from out_size
    const size_t ncell = (size_t)B * PNY * PNX;      // divisible by 4
    const size_t mapbytes = ncell * sizeof(int);
    const size_t zoff = (mapbytes + 255) & ~(size_t)255;
    const size_t need = zoff + PC * sizeof(float);

    if (ws_size >= need) {
        int*   map  = (int*)d_ws;
        float* zrow = (float*)((char*)d_ws + zoff);
        // 0xFF bytes == int32 -1 : empty-cell marker
        hipMemsetAsync(map, 0xFF, mapbytes, stream);
        pps_scatter_idx<<<(P + 255) / 256, 256, 0, stream>>>(coords, map, zrow, P);
        int n4 = (int)(ncell / 4);
        pps_gather<<<(n4 + 255) / 256, 256, 0, stream>>>(feat, map, zrow, out, n4);
    } else {
        int n4 = out_size / 4;
        pps_zero<<<(n4 + 255) / 256, 256, 0, stream>>>((float4*)out, n4);
        int total = P * PC;
        pps_scatter_feat<<<(total + 255) / 256, 256, 0, stream>>>(feat, coords, out, total);
    }
}